// Round 3
// baseline (369.772 us; speedup 1.0000x reference)
//
#include <hip/hip_runtime.h>

// GeometricMultiHeadAttention — MI355X bf16 pipeline, dtype-agnostic inputs
// B=2 L=1024 D=1024 H=16 HD=64 NBUCKETS=64

typedef __attribute__((ext_vector_type(8))) short short8;   // 8 bf16
typedef __attribute__((ext_vector_type(4))) short short4v;  // 4 bf16
typedef __attribute__((ext_vector_type(4))) float f32x4;    // 4 fp32

struct W6 { const unsigned short* p[6]; };
struct Src13 { const void* p[13]; };

__device__ __forceinline__ float bf2f(unsigned short u){
  union { unsigned u32; float f; } v; v.u32 = ((unsigned)u) << 16; return v.f;
}
__device__ __forceinline__ unsigned short f2bf(float f){
  unsigned u = __float_as_uint(f);
  u += 0x7FFFu + ((u >> 16) & 1u);            // RNE
  return (unsigned short)(u >> 16);
}
__device__ __forceinline__ void async16(const void* g, void* l){
  __builtin_amdgcn_global_load_lds(
      (const __attribute__((address_space(1))) unsigned int*)g,
      (__attribute__((address_space(3))) unsigned int*)l, 16, 0, 0);
}
__device__ __forceinline__ f32x4 mfma16(short8 a, short8 b, f32x4 c){
  return __builtin_amdgcn_mfma_f32_16x16x32_bf16(a, b, c, 0, 0, 0);
}
// freqs[i] = 2*pi / exp(i*ln(10000)/31), i in [0,32)
__device__ __forceinline__ float freq_of(int dd){
  return 6.283185307179586f * __expf(-0.29710775393471563f * (float)dd);
}

// Park element offsets (u16 units)
#define PX   0
#define PW(i) (2097152 + (i) * 1048576)   // i=0..6 : Wq Wk Wv Wo cWq cWk cWv
#define PQG  9437184
#define PQB  9438208
#define PKG  9439232
#define PKB  9440256
#define PBI  9441280
#define PARK_TOTAL 9442304                // elements

// ---------------------------------------------------------------------------
// K0: detect input float dtype (fp32 vs bf16) and convert everything into a
// bf16 "park". Each block re-detects (reads 512 B of x) — no cross-block dep.
// grid: 9221 blocks x 256 thr; block handles 1024 elements.
// ---------------------------------------------------------------------------
__global__ __launch_bounds__(256) void k_convert(
    Src13 src, unsigned short* __restrict__ park, int* __restrict__ flag)
{
  const int t = threadIdx.x;
  const int bid = blockIdx.x;
  __shared__ int shcnt;
  if (t == 0) shcnt = 0;
  __syncthreads();
  // detect: even-indexed u16 of x, interpreted as bf16 exponent field
  const unsigned short* xr = (const unsigned short*)src.p[0];
  int e = (xr[2 * t] >> 7) & 0xFF;
  unsigned long long m = __ballot(e >= 132);
  if ((t & 63) == 0) atomicAdd(&shcnt, __popcll(m));
  __syncthreads();
  const bool isf32 = shcnt > 64;

  int seg, inner;
  if (bid < 2048)      { seg = 0;                      inner = bid; }
  else if (bid < 9216) { seg = 1 + ((bid - 2048) >> 10); inner = (bid - 2048) & 1023; }
  else                 { seg = 8 + (bid - 9216);       inner = 0; }
  static const __device__ int segbase[13] = {
    PX, PW(0), PW(1), PW(2), PW(3), PW(4), PW(5), PW(6),
    PQG, PQB, PKG, PKB, PBI };
  unsigned short* dst = park + segbase[seg] + inner * 1024 + t * 4;
  if (isf32) {
    const float* s = (const float*)src.p[seg] + inner * 1024 + t * 4;
    f32x4 v = *(const f32x4*)s;
    short4v o;
    o.x = (short)f2bf(v.x); o.y = (short)f2bf(v.y);
    o.z = (short)f2bf(v.z); o.w = (short)f2bf(v.w);
    *(short4v*)dst = o;
  } else {
    const unsigned short* s = (const unsigned short*)src.p[seg] + inner * 1024 + t * 4;
    *(short4v*)dst = *(const short4v*)s;
  }
  if (bid == 0 && t == 0) *flag = isf32 ? 1 : 0;
}

// ---------------------------------------------------------------------------
// K1: Y[2048,6144] fp32 = X[2048,1024] @ [Wq Wk Wv cWq cWk cWv]^T
// ---------------------------------------------------------------------------
__global__ __launch_bounds__(256, 2) void k_proj_gemm(
    const unsigned short* __restrict__ X, W6 w6, float* __restrict__ Y)
{
  __shared__ unsigned short As[128 * 32];
  __shared__ unsigned short Bs[128 * 32];
  const int t = threadIdx.x;
  const int lane = t & 63, wid = t >> 6;
  const int m0 = blockIdx.x * 128;
  const int bn = blockIdx.y;                    // 0..47
  const unsigned short* W = w6.p[bn >> 3];
  const int nw0 = (bn & 7) * 128;               // row offset inside weight
  const int waveM = (wid & 1) * 64, waveN = (wid >> 1) * 64;
  const int g = lane >> 4, c16 = lane & 15;
  const int srow = t >> 2, scol = (t & 3) * 8;

  f32x4 acc[4][4];
  #pragma unroll
  for (int i = 0; i < 4; i++)
    #pragma unroll
    for (int j = 0; j < 4; j++) acc[i][j] = f32x4{0.f, 0.f, 0.f, 0.f};

  for (int k0 = 0; k0 < 1024; k0 += 32) {
    async16(X + (size_t)(m0 + srow) * 1024 + k0 + scol,       (char*)As + t * 16);
    async16(X + (size_t)(m0 + 64 + srow) * 1024 + k0 + scol,  (char*)As + 4096 + t * 16);
    async16(W + (size_t)(nw0 + srow) * 1024 + k0 + scol,      (char*)Bs + t * 16);
    async16(W + (size_t)(nw0 + 64 + srow) * 1024 + k0 + scol, (char*)Bs + 4096 + t * 16);
    __syncthreads();
    short8 af[4], bfr[4];
    #pragma unroll
    for (int mt = 0; mt < 4; mt++)
      af[mt] = *(const short8*)(As + (waveM + mt * 16 + c16) * 32 + g * 8);
    #pragma unroll
    for (int nt = 0; nt < 4; nt++)
      bfr[nt] = *(const short8*)(Bs + (waveN + nt * 16 + c16) * 32 + g * 8);
    #pragma unroll
    for (int mt = 0; mt < 4; mt++)
      #pragma unroll
      for (int nt = 0; nt < 4; nt++)
        acc[mt][nt] = mfma16(af[mt], bfr[nt], acc[mt][nt]);
    __syncthreads();
  }
  const int n0 = bn * 128;
  #pragma unroll
  for (int mt = 0; mt < 4; mt++)
    #pragma unroll
    for (int nt = 0; nt < 4; nt++)
      #pragma unroll
      for (int r = 0; r < 4; r++) {
        int row = m0 + waveM + mt * 16 + g * 4 + r;
        int col = n0 + waveN + nt * 16 + c16;
        Y[(size_t)row * 6144 + col] = acc[mt][nt][r];
      }
}

// ---------------------------------------------------------------------------
// K2: per (b,l) row: LN+rope(q,k), rope(v), cast(cq,ck,cv); transpose layouts.
// ---------------------------------------------------------------------------
__global__ __launch_bounds__(256) void k_post(
    const float* __restrict__ Y,
    const unsigned short* __restrict__ qg, const unsigned short* __restrict__ qbv,
    const unsigned short* __restrict__ kg, const unsigned short* __restrict__ kbv,
    const int* __restrict__ idx,
    unsigned short* __restrict__ qo, unsigned short* __restrict__ ko,
    unsigned short* __restrict__ cqo, unsigned short* __restrict__ cko,
    unsigned short* __restrict__ vto, unsigned short* __restrict__ cvto)
{
  const int r = blockIdx.x;              // b*L + l
  const int b = r >> 10, l = r & 1023;
  const int t = threadIdx.x;
  __shared__ float red[4];
  __shared__ float rowbuf[1024];
  const float* Yr = Y + (size_t)r * 6144;
  const float pos = (float)idx[r];

  for (int sec = 0; sec < 2; sec++) {
    const float* src = Yr + sec * 1024;
    const unsigned short* gg = sec ? kg : qg;
    const unsigned short* bb = sec ? kbv : qbv;
    unsigned short* dst = sec ? ko : qo;
    float v0 = src[t], v1 = src[t + 256], v2 = src[t + 512], v3 = src[t + 768];
    float s = v0 + v1 + v2 + v3;
    float s2 = v0 * v0 + v1 * v1 + v2 * v2 + v3 * v3;
    #pragma unroll
    for (int o = 32; o > 0; o >>= 1) {
      s += __shfl_down(s, o, 64);
      s2 += __shfl_down(s2, o, 64);
    }
    __syncthreads();
    if ((t & 63) == 0) red[t >> 6] = s;
    __syncthreads();
    float tot = red[0] + red[1] + red[2] + red[3];
    __syncthreads();
    if ((t & 63) == 0) red[t >> 6] = s2;
    __syncthreads();
    float tot2 = red[0] + red[1] + red[2] + red[3];
    float mu = tot * (1.f / 1024.f);
    float var = tot2 * (1.f / 1024.f) - mu * mu;
    float rstd = rsqrtf(var + 1e-5f);
    rowbuf[t]       = (v0 - mu) * rstd * bf2f(gg[t])       + bf2f(bb[t]);
    rowbuf[t + 256] = (v1 - mu) * rstd * bf2f(gg[t + 256]) + bf2f(bb[t + 256]);
    rowbuf[t + 512] = (v2 - mu) * rstd * bf2f(gg[t + 512]) + bf2f(bb[t + 512]);
    rowbuf[t + 768] = (v3 - mu) * rstd * bf2f(gg[t + 768]) + bf2f(bb[t + 768]);
    __syncthreads();
    #pragma unroll
    for (int j = 0; j < 4; j++) {
      int d = t + 256 * j;
      int h = d >> 6, dd = d & 63;
      float fr = freq_of(dd & 31);
      float a = pos * fr;
      float c = cosf(a), sn = sinf(a);
      float x1 = rowbuf[d];
      float x2 = rowbuf[(d & ~63) | ((dd + 32) & 63)];
      float res = (dd < 32) ? (x1 * c - x2 * sn) : (x1 * c + x2 * sn);
      dst[((size_t)(b * 16 + h) * 1024 + l) * 64 + dd] = f2bf(res);
    }
  }
  {
    const float* src = Yr + 2048;
    __syncthreads();
    rowbuf[t] = src[t]; rowbuf[t + 256] = src[t + 256];
    rowbuf[t + 512] = src[t + 512]; rowbuf[t + 768] = src[t + 768];
    __syncthreads();
    #pragma unroll
    for (int j = 0; j < 4; j++) {
      int d = t + 256 * j;
      int h = d >> 6, dd = d & 63;
      float fr = freq_of(dd & 31);
      float a = pos * fr;
      float c = cosf(a), sn = sinf(a);
      float x1 = rowbuf[d];
      float x2 = rowbuf[(d & ~63) | ((dd + 32) & 63)];
      float res = (dd < 32) ? (x1 * c - x2 * sn) : (x1 * c + x2 * sn);
      vto[((size_t)(b * 16 + h) * 64 + dd) * 1024 + l] = f2bf(res);
    }
  }
  #pragma unroll
  for (int j = 0; j < 4; j++) {
    int d = t + 256 * j;
    int h = d >> 6, dd = d & 63;
    size_t km = ((size_t)(b * 16 + h) * 1024 + l) * 64 + dd;
    cqo[km] = f2bf(Yr[3072 + d]);
    cko[km] = f2bf(Yr[4096 + d]);
    cvto[((size_t)(b * 16 + h) * 64 + dd) * 1024 + l] = f2bf(Yr[5120 + d]);
  }
}

// ---------------------------------------------------------------------------
// K3: scores. S = (spm? q.k : cq.ck)*scale + bias[z,h] -> bf16
// ---------------------------------------------------------------------------
__global__ __launch_bounds__(256, 2) void k_scores(
    const unsigned short* __restrict__ q, const unsigned short* __restrict__ k,
    const unsigned short* __restrict__ cq, const unsigned short* __restrict__ ck,
    const int* __restrict__ chain, const int* __restrict__ mol,
    const int* __restrict__ z, const unsigned short* __restrict__ bias,
    unsigned short* __restrict__ S)
{
  const int q0 = blockIdx.x * 128;
  const int k0 = blockIdx.y * 128;
  const int bh = blockIdx.z;
  const int b = bh >> 4, h = bh & 15;
  __shared__ unsigned short Qs[128 * 32], Ks[128 * 32], cQs[128 * 32], cKs[128 * 32];
  __shared__ float biasLDS[64];
  __shared__ int chq[128], chk[128], mok[128];
  const int t = threadIdx.x, lane = t & 63, wid = t >> 6;
  const int g = lane >> 4, c16 = lane & 15;
  const size_t basep = (size_t)bh * 1024 * 64;
  const int srow = t >> 2, scol = (t & 3) * 8;

  if (t < 64) biasLDS[t] = bf2f(bias[t * 16 + h]);
  if (t >= 64 && t < 192) {
    int u = t - 64;
    chq[u] = chain[b * 1024 + q0 + u];
    chk[u] = chain[b * 1024 + k0 + u];
    mok[u] = mol[b * 1024 + k0 + u];
  }

  const int waveM = (wid & 1) * 64, waveN = (wid >> 1) * 64;
  f32x4 accS[4][4], accC[4][4];
  #pragma unroll
  for (int i = 0; i < 4; i++)
    #pragma unroll
    for (int j = 0; j < 4; j++) {
      accS[i][j] = f32x4{0.f, 0.f, 0.f, 0.f};
      accC[i][j] = f32x4{0.f, 0.f, 0.f, 0.f};
    }

  #pragma unroll
  for (int half = 0; half < 2; half++) {
    const int kk0 = half * 32;
    async16(q  + basep + (size_t)(q0 + srow) * 64 + kk0 + scol,      (char*)Qs + t * 16);
    async16(q  + basep + (size_t)(q0 + 64 + srow) * 64 + kk0 + scol, (char*)Qs + 4096 + t * 16);
    async16(k  + basep + (size_t)(k0 + srow) * 64 + kk0 + scol,      (char*)Ks + t * 16);
    async16(k  + basep + (size_t)(k0 + 64 + srow) * 64 + kk0 + scol, (char*)Ks + 4096 + t * 16);
    async16(cq + basep + (size_t)(q0 + srow) * 64 + kk0 + scol,      (char*)cQs + t * 16);
    async16(cq + basep + (size_t)(q0 + 64 + srow) * 64 + kk0 + scol, (char*)cQs + 4096 + t * 16);
    async16(ck + basep + (size_t)(k0 + srow) * 64 + kk0 + scol,      (char*)cKs + t * 16);
    async16(ck + basep + (size_t)(k0 + 64 + srow) * 64 + kk0 + scol, (char*)cKs + 4096 + t * 16);
    __syncthreads();
    short8 aS[4], bS[4], aC[4], bC[4];
    #pragma unroll
    for (int mt = 0; mt < 4; mt++) {
      aS[mt] = *(const short8*)(Qs  + (waveM + mt * 16 + c16) * 32 + g * 8);
      aC[mt] = *(const short8*)(cQs + (waveM + mt * 16 + c16) * 32 + g * 8);
    }
    #pragma unroll
    for (int nt = 0; nt < 4; nt++) {
      bS[nt] = *(const short8*)(Ks  + (waveN + nt * 16 + c16) * 32 + g * 8);
      bC[nt] = *(const short8*)(cKs + (waveN + nt * 16 + c16) * 32 + g * 8);
    }
    #pragma unroll
    for (int mt = 0; mt < 4; mt++)
      #pragma unroll
      for (int nt = 0; nt < 4; nt++) {
        accS[mt][nt] = mfma16(aS[mt], bS[nt], accS[mt][nt]);
        accC[mt][nt] = mfma16(aC[mt], bC[nt], accC[mt][nt]);
      }
    __syncthreads();
  }
  #pragma unroll
  for (int mt = 0; mt < 4; mt++)
    #pragma unroll
    for (int nt = 0; nt < 4; nt++)
      #pragma unroll
      for (int r = 0; r < 4; r++) {
        int qr = waveM + mt * 16 + g * 4 + r;
        int kc = waveN + nt * 16 + c16;
        bool spm = (chk[kc] == chq[qr]) && (mok[kc] == 0);
        float s = (spm ? accS[mt][nt][r] : accC[mt][nt][r]) * 0.125f;
        int zv = z[(size_t)b * 1048576 + (size_t)(q0 + qr) * 1024 + (k0 + kc)];
        s += biasLDS[zv];
        S[(size_t)bh * 1048576 + (size_t)(q0 + qr) * 1024 + (k0 + kc)] = f2bf(s);
      }
}

// ---------------------------------------------------------------------------
// K4: softmax per (bh, q) row; wself written IN PLACE over S; wcross separate.
// ---------------------------------------------------------------------------
__global__ __launch_bounds__(256) void k_softmax(
    unsigned short* __restrict__ S,
    const int* __restrict__ chain, const int* __restrict__ mol,
    unsigned short* __restrict__ wcross)
{
  const int qi = blockIdx.x;
  const int bh = blockIdx.y;
  const int b = bh >> 4;
  const int t = threadIdx.x;
  __shared__ float red[4];
  unsigned short* row = S + (size_t)bh * 1048576 + (size_t)qi * 1024;
  float v[4];
  float mx = -1e30f;
  #pragma unroll
  for (int j = 0; j < 4; j++) { v[j] = bf2f(row[t + 256 * j]); mx = fmaxf(mx, v[j]); }
  #pragma unroll
  for (int o = 32; o > 0; o >>= 1) mx = fmaxf(mx, __shfl_down(mx, o, 64));
  if ((t & 63) == 0) red[t >> 6] = mx;
  __syncthreads();
  mx = fmaxf(fmaxf(red[0], red[1]), fmaxf(red[2], red[3]));
  float s = 0.f;
  #pragma unroll
  for (int j = 0; j < 4; j++) { v[j] = __expf(v[j] - mx); s += v[j]; }
  #pragma unroll
  for (int o = 32; o > 0; o >>= 1) s += __shfl_down(s, o, 64);
  __syncthreads();
  if ((t & 63) == 0) red[t >> 6] = s;
  __syncthreads();
  float inv = 1.f / (red[0] + red[1] + red[2] + red[3]);
  int cq = chain[b * 1024 + qi];
  #pragma unroll
  for (int j = 0; j < 4; j++) {
    int ki = t + 256 * j;
    float w = v[j] * inv;
    bool spm = (chain[b * 1024 + ki] == cq) && (mol[b * 1024 + ki] == 0);
    size_t o = (size_t)bh * 1048576 + (size_t)qi * 1024 + ki;
    S[o]      = f2bf(spm ? w : 0.f);      // wself in place
    wcross[o] = f2bf(spm ? 0.f : w);
  }
}

// ---------------------------------------------------------------------------
// K5: PV GEMMs + inverse rope + combine -> (B,L,D) bf16
// ---------------------------------------------------------------------------
__global__ __launch_bounds__(256, 2) void k_pv(
    const unsigned short* __restrict__ wself, const unsigned short* __restrict__ wcross,
    const unsigned short* __restrict__ vt, const unsigned short* __restrict__ cvt,
    const int* __restrict__ idx, unsigned short* __restrict__ comb)
{
  const int q0 = blockIdx.x * 128;
  const int bh = blockIdx.y;
  const int b = bh >> 4, h = bh & 15;
  __shared__ unsigned short Ws[128 * 32], Wc[128 * 32], Vs[64 * 32], Vc[64 * 32];
  const int t = threadIdx.x, lane = t & 63, wid = t >> 6;
  const int g = lane >> 4, c16 = lane & 15;
  const size_t wbase = (size_t)bh * 1048576;
  const size_t vbase = (size_t)bh * 64 * 1024;
  const int arow = t >> 2, acol = (t & 3) * 8;

  f32x4 accS[2][4], accC[2][4];
  #pragma unroll
  for (int i = 0; i < 2; i++)
    #pragma unroll
    for (int j = 0; j < 4; j++) {
      accS[i][j] = f32x4{0.f, 0.f, 0.f, 0.f};
      accC[i][j] = f32x4{0.f, 0.f, 0.f, 0.f};
    }

  for (int k0 = 0; k0 < 1024; k0 += 32) {
    async16(wself  + wbase + (size_t)(q0 + arow) * 1024 + k0 + acol,      (char*)Ws + t * 16);
    async16(wself  + wbase + (size_t)(q0 + 64 + arow) * 1024 + k0 + acol, (char*)Ws + 4096 + t * 16);
    async16(wcross + wbase + (size_t)(q0 + arow) * 1024 + k0 + acol,      (char*)Wc + t * 16);
    async16(wcross + wbase + (size_t)(q0 + 64 + arow) * 1024 + k0 + acol, (char*)Wc + 4096 + t * 16);
    async16(vt  + vbase + (size_t)arow * 1024 + k0 + acol, (char*)Vs + t * 16);
    async16(cvt + vbase + (size_t)arow * 1024 + k0 + acol, (char*)Vc + t * 16);
    __syncthreads();
    short8 aS[2], aC[2], bS[4], bC[4];
    #pragma unroll
    for (int mt = 0; mt < 2; mt++) {
      aS[mt] = *(const short8*)(Ws + (wid * 32 + mt * 16 + c16) * 32 + g * 8);
      aC[mt] = *(const short8*)(Wc + (wid * 32 + mt * 16 + c16) * 32 + g * 8);
    }
    #pragma unroll
    for (int nt = 0; nt < 4; nt++) {
      bS[nt] = *(const short8*)(Vs + (nt * 16 + c16) * 32 + g * 8);
      bC[nt] = *(const short8*)(Vc + (nt * 16 + c16) * 32 + g * 8);
    }
    #pragma unroll
    for (int mt = 0; mt < 2; mt++)
      #pragma unroll
      for (int nt = 0; nt < 4; nt++) {
        accS[mt][nt] = mfma16(aS[mt], bS[nt], accS[mt][nt]);
        accC[mt][nt] = mfma16(aC[mt], bC[nt], accC[mt][nt]);
      }
    __syncthreads();
  }
  #pragma unroll
  for (int mt = 0; mt < 2; mt++)
    #pragma unroll
    for (int r = 0; r < 4; r++) {
      int qr = q0 + wid * 32 + mt * 16 + g * 4 + r;
      float pos = (float)idx[b * 1024 + qr];
      #pragma unroll
      for (int nt = 0; nt < 2; nt++) {
        int d = nt * 16 + c16;                        // 0..31
        float fr = freq_of(d);
        float a = -pos * fr;
        float c = cosf(a), sn = sinf(a);
        float lo = accS[mt][nt][r], hi = accS[mt][nt + 2][r];
        float olo = lo * c - hi * sn;
        float ohi = hi * c + lo * sn;
        size_t o = ((size_t)(b * 1024 + qr)) * 1024 + h * 64;
        comb[o + d]      = f2bf(olo + accC[mt][nt][r]);
        comb[o + d + 32] = f2bf(ohi + accC[mt][nt + 2][r]);
      }
    }
}

// ---------------------------------------------------------------------------
// K6: out = comb @ Wo^T ; store bf16 or fp32 depending on detected dtype
// ---------------------------------------------------------------------------
__global__ __launch_bounds__(256, 2) void k_out_gemm(
    const unsigned short* __restrict__ A, const unsigned short* __restrict__ Wo,
    const int* __restrict__ flag, void* __restrict__ outv)
{
  __shared__ unsigned short As[128 * 32];
  __shared__ unsigned short Bs[128 * 32];
  const int t = threadIdx.x;
  const int lane = t & 63, wid = t >> 6;
  const int m0 = blockIdx.x * 128;
  const int n0 = blockIdx.y * 128;
  const int waveM = (wid & 1) * 64, waveN = (wid >> 1) * 64;
  const int g = lane >> 4, c16 = lane & 15;
  const int srow = t >> 2, scol = (t & 3) * 8;
  const int f32out = *flag;
  f32x4 acc[4][4];
  #pragma unroll
  for (int i = 0; i < 4; i++)
    #pragma unroll
    for (int j = 0; j < 4; j++) acc[i][j] = f32x4{0.f, 0.f, 0.f, 0.f};
  for (int k0 = 0; k0 < 1024; k0 += 32) {
    async16(A  + (size_t)(m0 + srow) * 1024 + k0 + scol,       (char*)As + t * 16);
    async16(A  + (size_t)(m0 + 64 + srow) * 1024 + k0 + scol,  (char*)As + 4096 + t * 16);
    async16(Wo + (size_t)(n0 + srow) * 1024 + k0 + scol,       (char*)Bs + t * 16);
    async16(Wo + (size_t)(n0 + 64 + srow) * 1024 + k0 + scol,  (char*)Bs + 4096 + t * 16);
    __syncthreads();
    short8 af[4], bfr[4];
    #pragma unroll
    for (int mt = 0; mt < 4; mt++)
      af[mt] = *(const short8*)(As + (waveM + mt * 16 + c16) * 32 + g * 8);
    #pragma unroll
    for (int nt = 0; nt < 4; nt++)
      bfr[nt] = *(const short8*)(Bs + (waveN + nt * 16 + c16) * 32 + g * 8);
    #pragma unroll
    for (int mt = 0; mt < 4; mt++)
      #pragma unroll
      for (int nt = 0; nt < 4; nt++)
        acc[mt][nt] = mfma16(af[mt], bfr[nt], acc[mt][nt]);
    __syncthreads();
  }
  #pragma unroll
  for (int mt = 0; mt < 4; mt++)
    #pragma unroll
    for (int nt = 0; nt < 4; nt++)
      #pragma unroll
      for (int r = 0; r < 4; r++) {
        int row = m0 + waveM + mt * 16 + g * 4 + r;
        int col = n0 + waveN + nt * 16 + c16;
        if (f32out) ((float*)outv)[(size_t)row * 1024 + col] = acc[mt][nt][r];
        else ((unsigned short*)outv)[(size_t)row * 1024 + col] = f2bf(acc[mt][nt][r]);
      }
}

// ---------------------------------------------------------------------------
extern "C" void kernel_launch(void* const* d_in, const int* in_sizes, int n_in,
                              void* d_out, int out_size, void* d_ws, size_t ws_size,
                              hipStream_t stream)
{
  (void)in_sizes; (void)n_in; (void)out_size; (void)ws_size;
  const int* z     = (const int*)d_in[1];
  const int* idx   = (const int*)d_in[3];
  const int* chain = (const int*)d_in[4];
  const int* mol   = (const int*)d_in[5];

  char* ws = (char*)d_ws;
  float*          Y     = (float*)ws;                       // 48 MB fp32
  unsigned short* S     = (unsigned short*)ws;              // 64 MB bf16 (reuse)
  size_t off = 67108864;
  unsigned short* qbuf  = (unsigned short*)(ws + off); off += 4194304;
  unsigned short* kbuf  = (unsigned short*)(ws + off); off += 4194304;
  unsigned short* cqbuf = (unsigned short*)(ws + off); off += 4194304;
  unsigned short* ckbuf = (unsigned short*)(ws + off); off += 4194304;
  unsigned short* vtbuf = (unsigned short*)(ws + off); off += 4194304;
  unsigned short* cvtbuf= (unsigned short*)(ws + off); off += 4194304;
  unsigned short* comb  = (unsigned short*)(ws + off); off += 4194304;   // ends 92MB
  unsigned short* wcrosb= (unsigned short*)(ws + off); off += 67108864;  // ends 156MB
  unsigned short* park  = (unsigned short*)(ws + off); off += (size_t)PARK_TOTAL * 2;
  int*            flag  = (int*)(ws + 183500800);

  Src13 src;
  src.p[0]  = d_in[0];   // x
  src.p[1]  = d_in[6];   // Wq
  src.p[2]  = d_in[7];   // Wk
  src.p[3]  = d_in[8];   // Wv
  src.p[4]  = d_in[9];   // Wo
  src.p[5]  = d_in[10];  // cWq
  src.p[6]  = d_in[11];  // cWk
  src.p[7]  = d_in[12];  // cWv
  src.p[8]  = d_in[13];  // qg
  src.p[9]  = d_in[14];  // qb
  src.p[10] = d_in[15];  // kg
  src.p[11] = d_in[16];  // kb
  src.p[12] = d_in[17];  // attn_bias

  W6 w6;
  w6.p[0] = park + PW(0);  // Wq
  w6.p[1] = park + PW(1);  // Wk
  w6.p[2] = park + PW(2);  // Wv
  w6.p[3] = park + PW(4);  // cWq
  w6.p[4] = park + PW(5);  // cWk
  w6.p[5] = park + PW(6);  // cWv

  k_convert<<<9221, 256, 0, stream>>>(src, park, flag);
  k_proj_gemm<<<dim3(16, 48), 256, 0, stream>>>(park + PX, w6, Y);
  k_post<<<2048, 256, 0, stream>>>(Y, park + PQG, park + PQB, park + PKG, park + PKB,
                                   idx, qbuf, kbuf, cqbuf, ckbuf, vtbuf, cvtbuf);
  k_scores<<<dim3(8, 8, 32), 256, 0, stream>>>(qbuf, kbuf, cqbuf, ckbuf,
                                               chain, mol, z, park + PBI, S);
  k_softmax<<<dim3(1024, 32), 256, 0, stream>>>(S, chain, mol, wcrosb);
  k_pv<<<dim3(8, 32), 256, 0, stream>>>(S, wcrosb, vtbuf, cvtbuf, idx, comb);
  k_out_gemm<<<dim3(16, 8), 256, 0, stream>>>(comb, park + PW(3), flag, d_out);
}